// Round 4
// baseline (751.310 us; speedup 1.0000x reference)
//
#include <hip/hip_runtime.h>

constexpr int N_NODES = 100000;
constexpr int D       = 64;
constexpr int N_EDGES = 1600000;
constexpr int OUT_N4  = N_NODES * D / 4;

// Bucketed counting-sort parameters
constexpr int NPB   = 128;                           // nodes per bucket
constexpr int NBUCK = (N_NODES + NPB - 1) / NPB;     // 782
constexpr int BCAP  = 2560;                          // slots per bucket (λ=2046, +11σ)
constexpr int CPAD  = 32;                            // cursor pad (ints) = 128B/line
constexpr int CHUNK = 8192;                          // edges per partition block
constexpr int PB    = (N_EDGES + CHUNK - 1) / CHUNK; // 196

// ---------------------------------------------------------------------------
__global__ void detect_kernel(const unsigned long long* __restrict__ ei,
                              int* __restrict__ flag) {
    if (blockIdx.x == 0 && threadIdx.x == 0) {
        int is64 = 1;
#pragma unroll
        for (int i = 0; i < 8; ++i)
            if (ei[i] >= (unsigned long long)N_NODES) is64 = 0;
        *flag = is64;
    }
}

__device__ __forceinline__ int load_idx(const void* ei_raw, int flag, long long pos) {
    if (flag) return (int)((const long long*)ei_raw)[pos];
    return ((const int*)ei_raw)[pos];
}

__global__ void zero_cursor_kernel(int* __restrict__ cursor) {
    int i = blockIdx.x * blockDim.x + threadIdx.x;
    if (i < NBUCK * CPAD) cursor[i] = 0;
}

// ---------------------------------------------------------------------------
// Pass 1: partition edges into 782 buckets of 128 dst-nodes each.
// Per block: LDS histogram -> one global atomic per (block,bucket) to reserve
// a contiguous run -> re-read chunk (L2-hot) and write 8B records into the
// bucket's run. Record: rec.x = (src<<7)|dstLocal, rec.y = bits(ew).
__global__ __launch_bounds__(256) void part_kernel(
        const void* __restrict__ ei_raw,
        const float* __restrict__ ew,
        const int* __restrict__ flag,
        int* __restrict__ cursor,
        int2* __restrict__ slots) {
    __shared__ int hist[NBUCK];
    __shared__ int fill[NBUCK];
    __shared__ int runbase[NBUCK];
    int tid = threadIdx.x;
    for (int t = tid; t < NBUCK; t += 256) { hist[t] = 0; fill[t] = 0; }
    __syncthreads();

    int f = *flag;
    long long base = (long long)blockIdx.x * CHUNK;

    // Phase A: local histogram of dst buckets
    for (int it = 0; it < CHUNK / 256; ++it) {
        long long e = base + it * 256 + tid;
        if (e < N_EDGES) {
            int dst = load_idx(ei_raw, f, (long long)N_EDGES + e);
            atomicAdd(&hist[dst >> 7], 1);
        }
    }
    __syncthreads();

    // Phase B: reserve runs in global bucket arrays
    for (int t = tid; t < NBUCK; t += 256) {
        int c = hist[t];
        runbase[t] = (c > 0) ? atomicAdd(&cursor[t * CPAD], c) : 0;
    }
    __syncthreads();

    // Phase C: re-read chunk and scatter records into contiguous runs
    for (int it = 0; it < CHUNK / 256; ++it) {
        long long e = base + it * 256 + tid;
        if (e < N_EDGES) {
            int src = load_idx(ei_raw, f, e);
            int dst = load_idx(ei_raw, f, (long long)N_EDGES + e);
            int b  = dst >> 7;
            int dl = dst & (NPB - 1);
            int r  = atomicAdd(&fill[b], 1);
            int idx = runbase[b] + r;
            if (idx < BCAP) {
                int2 rec;
                rec.x = (src << 7) | dl;
                rec.y = __float_as_int(ew[e]);
                slots[(long long)b * BCAP + idx] = rec;
            }
        }
    }
}

// ---------------------------------------------------------------------------
// Pass 2: one block per bucket. LDS accumulator acc[128][64]. Records read
// coalesced into LDS tile; each wave (lane=dim) processes 64 records per tile:
// random x[src] 256B load + conflict-free ds_add_f32 into the node row.
// Fused epilogue: out = relu(x + w*acc).
__global__ __launch_bounds__(256) void gather_bucket_kernel(
        const float* __restrict__ x,
        const int* __restrict__ cursor,
        const int2* __restrict__ slots,
        const float* __restrict__ weight,
        float* __restrict__ out) {
    __shared__ float acc[NPB * 64];   // 32 KB
    __shared__ int2 recs[256];        // 2 KB
    int tid  = threadIdx.x;
    int lane = tid & 63;
    int wv   = tid >> 6;
    int bucket = blockIdx.x;

    for (int i = tid; i < NPB * 64; i += 256) acc[i] = 0.f;

    int cnt = cursor[bucket * CPAD];
    if (cnt > BCAP) cnt = BCAP;
    const int2* sb = slots + (long long)bucket * BCAP;
    __syncthreads();

    for (int t0 = 0; t0 < cnt; t0 += 256) {
        int nrec = cnt - t0;
        if (nrec > 256) nrec = 256;
        if (tid < nrec) recs[tid] = sb[t0 + tid];
        __syncthreads();

        int rbase = wv * 64;
        int rcnt  = nrec - rbase;
        if (rcnt < 0) rcnt = 0;
        if (rcnt > 64) rcnt = 64;

        int j = 0;
        for (; j + 4 <= rcnt; j += 4) {
            int2 r0 = recs[rbase + j];
            int2 r1 = recs[rbase + j + 1];
            int2 r2 = recs[rbase + j + 2];
            int2 r3 = recs[rbase + j + 3];
            float v0 = __int_as_float(r0.y) * x[(r0.x >> 7) * D + lane];
            float v1 = __int_as_float(r1.y) * x[(r1.x >> 7) * D + lane];
            float v2 = __int_as_float(r2.y) * x[(r2.x >> 7) * D + lane];
            float v3 = __int_as_float(r3.y) * x[(r3.x >> 7) * D + lane];
            atomicAdd(&acc[(r0.x & (NPB - 1)) * 64 + lane], v0);
            atomicAdd(&acc[(r1.x & (NPB - 1)) * 64 + lane], v1);
            atomicAdd(&acc[(r2.x & (NPB - 1)) * 64 + lane], v2);
            atomicAdd(&acc[(r3.x & (NPB - 1)) * 64 + lane], v3);
        }
        for (; j < rcnt; ++j) {
            int2 r0 = recs[rbase + j];
            atomicAdd(&acc[(r0.x & (NPB - 1)) * 64 + lane],
                      __int_as_float(r0.y) * x[(r0.x >> 7) * D + lane]);
        }
        __syncthreads();
    }

    // Epilogue: out = relu(x + w*acc), coalesced 256B per wave-row
    float W = weight[0];
    int nodebase = bucket * NPB;
    for (int dl = wv; dl < NPB; dl += 4) {
        int node = nodebase + dl;
        if (node < N_NODES) {
            float r = x[node * D + lane] + W * acc[dl * 64 + lane];
            out[node * D + lane] = fmaxf(r, 0.f);
        }
    }
}

// ---------------------------------------------------------------------------
// Fallback: round-1 atomic path (only if ws is tiny)
__global__ void init_out_kernel(const float4* __restrict__ x4,
                                float4* __restrict__ out4) {
    int i = blockIdx.x * blockDim.x + threadIdx.x;
    int stride = gridDim.x * blockDim.x;
    for (; i < OUT_N4; i += stride) out4[i] = x4[i];
}

__global__ __launch_bounds__(256) void scatter_atomic_kernel(
        const float* __restrict__ x,
        const void* __restrict__ ei_raw,
        const float* __restrict__ ew,
        const float* __restrict__ weight,
        const int* __restrict__ flag,
        float* __restrict__ out) {
    long long gid = (long long)blockIdx.x * blockDim.x + threadIdx.x;
    int e = (int)(gid >> 6);
    int d = (int)(gid & 63);
    if (e >= N_EDGES) return;
    int f = *flag;
    int src = load_idx(ei_raw, f, e);
    int dst = load_idx(ei_raw, f, (long long)N_EDGES + e);
    float w = weight[0] * ew[e];
    atomicAdd(&out[dst * D + d], w * x[src * D + d]);
}

__global__ void relu_kernel(float4* __restrict__ out4) {
    int i = blockIdx.x * blockDim.x + threadIdx.x;
    int stride = gridDim.x * blockDim.x;
    for (; i < OUT_N4; i += stride) {
        float4 v = out4[i];
        v.x = fmaxf(v.x, 0.0f);
        v.y = fmaxf(v.y, 0.0f);
        v.z = fmaxf(v.z, 0.0f);
        v.w = fmaxf(v.w, 0.0f);
        out4[i] = v;
    }
}

// ---------------------------------------------------------------------------
extern "C" void kernel_launch(void* const* d_in, const int* in_sizes, int n_in,
                              void* d_out, int out_size, void* d_ws, size_t ws_size,
                              hipStream_t stream) {
    const float* x      = (const float*)d_in[0];
    const void*  ei     = d_in[1];
    const float* ew     = (const float*)d_in[2];
    const float* weight = (const float*)d_in[3];
    float* out = (float*)d_out;

    char* w = (char*)d_ws;
    int* flag = (int*)w;                          // 256B reserved

    size_t cur_off  = 256;
    size_t cur_size = (size_t)NBUCK * CPAD * 4;   // ~100 KB
    size_t slot_off = (cur_off + cur_size + 255) & ~(size_t)255;
    size_t slot_size = (size_t)NBUCK * BCAP * 8;  // ~16 MB
    size_t needed = slot_off + slot_size;

    detect_kernel<<<1, 64, 0, stream>>>((const unsigned long long*)ei, flag);

    if (ws_size >= needed) {
        int*  cursor = (int*)(w + cur_off);
        int2* slots  = (int2*)(w + slot_off);
        zero_cursor_kernel<<<(NBUCK * CPAD + 255) / 256, 256, 0, stream>>>(cursor);
        part_kernel<<<PB, 256, 0, stream>>>(ei, ew, flag, cursor, slots);
        gather_bucket_kernel<<<NBUCK, 256, 0, stream>>>(x, cursor, slots, weight, out);
    } else {
        init_out_kernel<<<2048, 256, 0, stream>>>((const float4*)x, (float4*)out);
        long long total = (long long)N_EDGES * 64;
        scatter_atomic_kernel<<<(int)((total + 255) / 256), 256, 0, stream>>>(
            x, ei, ew, weight, flag, out);
        relu_kernel<<<2048, 256, 0, stream>>>((float4*)out);
    }
}

// Round 5
// 134.175 us; speedup vs baseline: 5.5995x; 5.5995x over previous
//
#include <hip/hip_runtime.h>

constexpr int N_NODES = 100000;
constexpr int D       = 64;
constexpr int N_EDGES = 1600000;
constexpr int OUT_N4  = N_NODES * D / 4;

// bucketed counting-sort parameters
constexpr int NPB   = 128;                           // nodes per bucket
constexpr int NBUCK = (N_NODES + NPB - 1) / NPB;     // 782
constexpr int BCAP  = 2560;                          // slots/bucket (λ=2046, +11σ)
constexpr int CPAD  = 32;                            // cursor pad (ints) = 128B/line
constexpr int CHUNK = 4096;                          // edges per partition block
constexpr int PB    = (N_EDGES + CHUNK - 1) / CHUNK; // 391

// ---------------------------------------------------------------------------
__global__ void detect_kernel(const unsigned long long* __restrict__ ei,
                              int* __restrict__ flag) {
    if (blockIdx.x == 0 && threadIdx.x == 0) {
        int is64 = 1;
#pragma unroll
        for (int i = 0; i < 8; ++i)
            if (ei[i] >= (unsigned long long)N_NODES) is64 = 0;
        *flag = is64;
    }
}

__device__ __forceinline__ int load_idx(const void* ei_raw, int flag, long long pos) {
    if (flag) return (int)((const long long*)ei_raw)[pos];
    return ((const int*)ei_raw)[pos];
}

__global__ void zero_cursor_kernel(int* __restrict__ cursor) {
    int i = blockIdx.x * blockDim.x + threadIdx.x;
    if (i < NBUCK * CPAD) cursor[i] = 0;
}

// ---------------------------------------------------------------------------
// Pass 1: partition edges into 782 buckets of 128 dst-nodes.
// Per block: LDS bucket-histogram -> one global atomic per (block,bucket)
// reserves a contiguous run -> records written into the run.
// rec.x = (src<<7)|dstLocal, rec.y = bits(ew).
__global__ __launch_bounds__(256) void part_kernel(
        const void* __restrict__ ei_raw,
        const float* __restrict__ ew,
        const int* __restrict__ flag,
        int* __restrict__ cursor,
        int2* __restrict__ slots) {
    __shared__ int hist[NBUCK];
    __shared__ int fill[NBUCK];
    __shared__ int runbase[NBUCK];
    int tid = threadIdx.x;
    for (int t = tid; t < NBUCK; t += 256) { hist[t] = 0; fill[t] = 0; }
    __syncthreads();

    int f = *flag;
    long long base = (long long)blockIdx.x * CHUNK;

    for (int it = 0; it < CHUNK / 256; ++it) {
        long long e = base + it * 256 + tid;
        if (e < N_EDGES) {
            int dst = load_idx(ei_raw, f, (long long)N_EDGES + e);
            atomicAdd(&hist[dst >> 7], 1);
        }
    }
    __syncthreads();

    for (int t = tid; t < NBUCK; t += 256) {
        int c = hist[t];
        runbase[t] = (c > 0) ? atomicAdd(&cursor[t * CPAD], c) : 0;
    }
    __syncthreads();

    for (int it = 0; it < CHUNK / 256; ++it) {
        long long e = base + it * 256 + tid;
        if (e < N_EDGES) {
            int src = load_idx(ei_raw, f, e);
            int dst = load_idx(ei_raw, f, (long long)N_EDGES + e);
            int b  = dst >> 7;
            int dl = dst & (NPB - 1);
            int r  = atomicAdd(&fill[b], 1);
            int idx = runbase[b] + r;
            if (idx < BCAP) {
                int2 rec;
                rec.x = (src << 7) | dl;
                rec.y = __float_as_int(ew[e]);
                slots[(long long)b * BCAP + idx] = rec;
            }
        }
    }
}

// ---------------------------------------------------------------------------
// Pass 2: per-bucket LDS counting sort by local node id.
// One block per bucket: stage records in LDS, histogram over 128 nodes,
// exclusive scan, in-LDS placement, coalesced write-out of the node-sorted
// records + per-node {beg,cnt}.
__global__ __launch_bounds__(256) void sort_bucket_kernel(
        const int* __restrict__ cursor,
        const int2* __restrict__ slots,
        int2* __restrict__ sorted,
        int2* __restrict__ oc /* per-node {beg,cnt} */) {
    __shared__ int  hist[NPB];
    __shared__ int  scn[NPB];
    __shared__ int  fill[NPB];
    __shared__ int2 raw[BCAP];
    __shared__ int2 srt[BCAP];

    int tid = threadIdx.x;
    int b   = blockIdx.x;

    if (tid < NPB) { hist[tid] = 0; fill[tid] = 0; }
    __syncthreads();

    int cnt = cursor[b * CPAD];
    if (cnt > BCAP) cnt = BCAP;
    const int2* sb = slots + (long long)b * BCAP;

    // stage + histogram
    for (int i = tid; i < cnt; i += 256) {
        int2 r = sb[i];
        raw[i] = r;
        atomicAdd(&hist[r.x & (NPB - 1)], 1);
    }
    __syncthreads();

    // inclusive scan of hist -> scn (Hillis-Steele over 128)
    if (tid < NPB) scn[tid] = hist[tid];
    __syncthreads();
    for (int off = 1; off < NPB; off <<= 1) {
        int v = 0;
        if (tid < NPB && tid >= off) v = scn[tid - off];
        __syncthreads();
        if (tid < NPB) scn[tid] += v;
        __syncthreads();
    }

    // per-node {beg,cnt} out
    if (tid < NPB) {
        int node = b * NPB + tid;
        if (node < N_NODES) {
            int2 v;
            v.x = b * BCAP + (scn[tid] - hist[tid]);  // global beg
            v.y = hist[tid];
            oc[node] = v;
        }
    }
    __syncthreads();

    // placement into sorted LDS
    for (int i = tid; i < cnt; i += 256) {
        int2 r = raw[i];
        int dl = r.x & (NPB - 1);
        int pos = (scn[dl] - hist[dl]) + atomicAdd(&fill[dl], 1);
        srt[pos] = r;
    }
    __syncthreads();

    // coalesced write-out
    int2* ob = sorted + (long long)b * BCAP;
    for (int i = tid; i < cnt; i += 256) ob[i] = srt[i];
}

// ---------------------------------------------------------------------------
// Pass 3: gather — one wave per node, lane = feature dim, unroll-4.
__global__ __launch_bounds__(256) void gather_csr_kernel(
        const float* __restrict__ x,
        const int2* __restrict__ oc,
        const int2* __restrict__ sorted,
        const float* __restrict__ weight,
        float* __restrict__ out) {
    int lane = threadIdx.x & 63;
    int node = (blockIdx.x * blockDim.x + threadIdx.x) >> 6;
    if (node >= N_NODES) return;

    int2 v = oc[node];
    const int2* s = sorted + v.x;
    int cnt = v.y;

    float a0 = 0.f, a1 = 0.f, a2 = 0.f, a3 = 0.f;
    int k = 0;
    for (; k + 4 <= cnt; k += 4) {
        int2 r0 = s[k];
        int2 r1 = s[k + 1];
        int2 r2 = s[k + 2];
        int2 r3 = s[k + 3];
        a0 += __int_as_float(r0.y) * x[(r0.x >> 7) * D + lane];
        a1 += __int_as_float(r1.y) * x[(r1.x >> 7) * D + lane];
        a2 += __int_as_float(r2.y) * x[(r2.x >> 7) * D + lane];
        a3 += __int_as_float(r3.y) * x[(r3.x >> 7) * D + lane];
    }
    for (; k < cnt; ++k) {
        int2 r0 = s[k];
        a0 += __int_as_float(r0.y) * x[(r0.x >> 7) * D + lane];
    }
    float acc = (a0 + a1) + (a2 + a3);

    float r = x[node * D + lane] + weight[0] * acc;
    out[node * D + lane] = fmaxf(r, 0.f);
}

// ---------------------------------------------------------------------------
// Fallback: atomic path (only if ws is tiny)
__global__ void init_out_kernel(const float4* __restrict__ x4,
                                float4* __restrict__ out4) {
    int i = blockIdx.x * blockDim.x + threadIdx.x;
    int stride = gridDim.x * blockDim.x;
    for (; i < OUT_N4; i += stride) out4[i] = x4[i];
}

__global__ __launch_bounds__(256) void scatter_atomic_kernel(
        const float* __restrict__ x,
        const void* __restrict__ ei_raw,
        const float* __restrict__ ew,
        const float* __restrict__ weight,
        const int* __restrict__ flag,
        float* __restrict__ out) {
    long long gid = (long long)blockIdx.x * blockDim.x + threadIdx.x;
    int e = (int)(gid >> 6);
    int d = (int)(gid & 63);
    if (e >= N_EDGES) return;
    int f = *flag;
    int src = load_idx(ei_raw, f, e);
    int dst = load_idx(ei_raw, f, (long long)N_EDGES + e);
    float w = weight[0] * ew[e];
    atomicAdd(&out[dst * D + d], w * x[src * D + d]);
}

__global__ void relu_kernel(float4* __restrict__ out4) {
    int i = blockIdx.x * blockDim.x + threadIdx.x;
    int stride = gridDim.x * blockDim.x;
    for (; i < OUT_N4; i += stride) {
        float4 v = out4[i];
        v.x = fmaxf(v.x, 0.0f);
        v.y = fmaxf(v.y, 0.0f);
        v.z = fmaxf(v.z, 0.0f);
        v.w = fmaxf(v.w, 0.0f);
        out4[i] = v;
    }
}

// ---------------------------------------------------------------------------
extern "C" void kernel_launch(void* const* d_in, const int* in_sizes, int n_in,
                              void* d_out, int out_size, void* d_ws, size_t ws_size,
                              hipStream_t stream) {
    const float* x      = (const float*)d_in[0];
    const void*  ei     = d_in[1];
    const float* ew     = (const float*)d_in[2];
    const float* weight = (const float*)d_in[3];
    float* out = (float*)d_out;

    char* w = (char*)d_ws;
    int* flag = (int*)w;                                   // 256B reserved

    size_t cur_off   = 256;
    size_t cur_size  = (size_t)NBUCK * CPAD * 4;           // ~100 KB
    size_t slot_off  = (cur_off + cur_size + 255) & ~(size_t)255;
    size_t slot_size = (size_t)NBUCK * BCAP * 8;           // ~16 MB
    size_t sort_off  = slot_off + slot_size;
    size_t sort_size = slot_size;                          // ~16 MB
    size_t oc_off    = sort_off + sort_size;
    size_t oc_size   = (size_t)N_NODES * 8;                // 800 KB
    size_t needed    = oc_off + oc_size;

    detect_kernel<<<1, 64, 0, stream>>>((const unsigned long long*)ei, flag);

    if (ws_size >= needed) {
        int*  cursor = (int*)(w + cur_off);
        int2* slots  = (int2*)(w + slot_off);
        int2* sorted = (int2*)(w + sort_off);
        int2* oc     = (int2*)(w + oc_off);

        zero_cursor_kernel<<<(NBUCK * CPAD + 255) / 256, 256, 0, stream>>>(cursor);
        part_kernel<<<PB, 256, 0, stream>>>(ei, ew, flag, cursor, slots);
        sort_bucket_kernel<<<NBUCK, 256, 0, stream>>>(cursor, slots, sorted, oc);
        gather_csr_kernel<<<(N_NODES * 64 + 255) / 256, 256, 0, stream>>>(
            x, oc, sorted, weight, out);
    } else {
        init_out_kernel<<<2048, 256, 0, stream>>>((const float4*)x, (float4*)out);
        long long total = (long long)N_EDGES * 64;
        scatter_atomic_kernel<<<(int)((total + 255) / 256), 256, 0, stream>>>(
            x, ei, ew, weight, flag, out);
        relu_kernel<<<2048, 256, 0, stream>>>((float4*)out);
    }
}